// Round 6
// baseline (670.017 us; speedup 1.0000x reference)
//
#include <hip/hip_runtime.h>
#include <hip/hip_cooperative_groups.h>
#include <math.h>

namespace cg = cooperative_groups;

#define BS   32
#define NV   6
#define MF   12
#define MT   16
#define NF   1992
#define NR   11
#define HID  128
#define RED  256
#define OUTD 90
#define GAMMA 0.1f
#define NZCAP 1024

typedef float f4_t __attribute__((ext_vector_type(4)));

// workspace layout (float offsets)
#define WS_HG    0                        // 32*256
#define WS_HP    (WS_HG + BS*RED)         // 32*256
#define WS_ATTN  (WS_HP + BS*RED)         // 2304
#define WS_FSUM  (WS_ATTN + BS*NV*MF)     // 2304
#define WS_REMB  (WS_FSUM + BS*NV*MF)     // 1992*256
#define WS_REDGE (WS_REMB + NF*RED)       // 11*256
#define WS_WTV   (WS_REDGE + NR*RED)      // 128*256  (W_v^T, k-major)
#define WS_WTR   (WS_WTV + HID*RED)       // 128*256  (W_r^T, k-major)
#define WS_FCWT  (WS_WTR + HID*RED)       // 512*90   (fc_W^T, j-major)
#define WS_DIAG  (WS_FCWT + 2*RED*OUTD)   // 256      (diag of W_l)
#define WS_CNT   (WS_DIAG + RED)          // 2304 ints
#define WS_RSUM  (WS_CNT + BS*NV*MF)      // 2304*11
#define WS_NZN   (WS_RSUM + BS*NV*MF*NR)  // 2304*1024 ints
#define WS_NZV   (WS_NZN + BS*NV*MF*NZCAP)// 2304*1024 floats

#define STREAM_BLOCKS (BS*NV*MF)          // 2304
#define ATTN_BLOCKS   (BS*NV)             // 192
#define N_ZERO (2*BS*RED)                 // 16384 (hg+hp contiguous)
#define N_WTV  (HID*RED)                  // 32768
#define N_WTR  (HID*RED)                  // 32768
#define N_FCWT (2*RED*OUTD)               // 46080
#define N_DIAG RED                        // 256
#define PREP_ELEMS (N_ZERO + N_WTV + N_WTR + N_FCWT + N_DIAG)   // 128256
#define PREP_BLOCKS (PREP_ELEMS / 256)                          // 501

#define NPB 8
#define NODE_BLOCKS (NF / NPB)            // 249
#define TAIL_GRID 1024

// ---------- K1: prep | attention | nbr stream+compact (stream LAST so small
// blocks hide under it; tail is uniform 128KB stream blocks) ----------
__global__ __launch_bounds__(256) void k_main(
        const float* __restrict__ nbr, const float* __restrict__ rel,
        const float* __restrict__ W_v, const float* __restrict__ W_r,
        const float* __restrict__ fc_W, const float* __restrict__ W_l,
        const float* __restrict__ feat, const float* __restrict__ W_alpha,
        const float* __restrict__ b_alpha, const float* __restrict__ W_beta,
        const float* __restrict__ b_beta,
        float* __restrict__ ws_base,
        float* __restrict__ WT_v, float* __restrict__ WT_r, float* __restrict__ fcWT,
        float* __restrict__ diag,
        int* __restrict__ cnt_g, float* __restrict__ rsum_g,
        int* __restrict__ nzn_g, float* __restrict__ nzv_g,
        float* __restrict__ attn_ws, float* __restrict__ fsum_ws) {
    int blk = blockIdx.x;
    int tid = threadIdx.x;

    if (blk < PREP_BLOCKS) {
        int i = blk * 256 + tid;
        if (i < N_ZERO) {                          // zero hg+hp
            ws_base[i] = 0.f;
        } else if (i < N_ZERO + N_WTV) {           // WT_v[k*256+r] = W_v[r*128+k]
            int j = i - N_ZERO;
            int k = j >> 8, r = j & 255;
            WT_v[j] = W_v[r * HID + k];
        } else if (i < N_ZERO + N_WTV + N_WTR) {
            int j = i - (N_ZERO + N_WTV);
            int k = j >> 8, r = j & 255;
            WT_r[j] = W_r[r * HID + k];
        } else if (i < N_ZERO + N_WTV + N_WTR + N_FCWT) {
            int j = i - (N_ZERO + N_WTV + N_WTR);  // j = jj*90 + o
            int jj = j / OUTD, o = j - jj * OUTD;
            fcWT[j] = fc_W[o * (2 * RED) + jj];
        } else {
            int j = i - (N_ZERO + N_WTV + N_WTR + N_FCWT);
            diag[j] = W_l[(size_t)j * RED + j];
        }
        return;
    }
    blk -= PREP_BLOCKS;

    if (blk < ATTN_BLOCKS) {
        // ---- attention: one block per (b,v), one wave per m ----
        int bv   = blk;                            // 0..191
        int v    = bv % NV;
        int wave = tid >> 6;
        int lane = tid & 63;
        __shared__ float dot12[MF], fs12[MF];
        const float* base = feat + (size_t)bv * MF * NF;
        for (int m = wave; m < MF; m += 4) {
            const float4* rw = (const float4*)(base + (size_t)m * NF);   // 498 float4
            const float4* wa = (const float4*)W_alpha;
            float da = 0.f, fs = 0.f;
            for (int i = lane; i < NF / 4; i += 64) {
                float4 x = rw[i];
                float4 w = wa[i];
                da += w.x * x.x + w.y * x.y + w.z * x.z + w.w * x.w;
                fs += x.x + x.y + x.z + x.w;
            }
            #pragma unroll
            for (int off = 32; off > 0; off >>= 1) {
                da += __shfl_xor(da, off);
                fs += __shfl_xor(fs, off);
            }
            if (lane == 0) { dot12[m] = da; fs12[m] = fs; }
        }
        __syncthreads();
        if (tid == 0) {
            float logits[MF];
            float mx = -1e30f;
            for (int m = 0; m < MF; ++m) { logits[m] = dot12[m] + b_alpha[m]; mx = fmaxf(mx, logits[m]); }
            float s = 0.f;
            for (int m = 0; m < MF; ++m) { logits[m] = expf(logits[m] - mx); s += logits[m]; }
            float inv = 1.f / s;
            float bdot = 0.f;
            for (int m = 0; m < MF; ++m) { logits[m] *= inv; bdot += W_beta[m] * logits[m]; }
            float lamb = expf(-GAMMA * (float)(NV - v));
            float beta = tanhf(bdot + b_beta[v]) * lamb;
            for (int m = 0; m < MF; ++m) {
                attn_ws[bv * MF + m] = logits[m] * beta;
                fsum_ws[bv * MF + m] = fs12[m];
            }
        }
        return;
    }
    blk -= ATTN_BLOCKS;

    // ---- the 294 MB long pole: stream nbr, sum over t, compact nonzeros ----
    int bvm = blk;
    __shared__ int   nz_n[NZCAP];
    __shared__ float nz_v[NZCAP];
    __shared__ float relbuf[MT * NR];       // 176 floats, contiguous in global
    __shared__ int   cnt;
    if (tid == 0) cnt = 0;
    if (tid < MT * NR / 4) {                // 44 float4 = whole rel slice
        ((f4_t*)relbuf)[tid] = ((const f4_t*)(rel + (size_t)bvm * MT * NR))[tid];
    }

    const f4_t* base = (const f4_t*)(nbr + (size_t)bvm * MT * NF);  // row = 498 f4
    f4_t x[8];
    f4_t a0 = (f4_t)(0.f);
    f4_t a1 = (f4_t)(0.f);
    #pragma unroll
    for (int t = 0; t < 8; ++t) x[t] = __builtin_nontemporal_load(base + t * (NF/4) + tid);
    #pragma unroll
    for (int t = 0; t < 8; ++t) a0 += x[t];
    #pragma unroll
    for (int t = 0; t < 8; ++t) x[t] = __builtin_nontemporal_load(base + (t + 8) * (NF/4) + tid);
    #pragma unroll
    for (int t = 0; t < 8; ++t) a0 += x[t];
    const bool has1 = (tid + 256) < (NF / 4);
    if (has1) {
        #pragma unroll
        for (int t = 0; t < 8; ++t) x[t] = __builtin_nontemporal_load(base + t * (NF/4) + tid + 256);
        #pragma unroll
        for (int t = 0; t < 8; ++t) a1 += x[t];
        #pragma unroll
        for (int t = 0; t < 8; ++t) x[t] = __builtin_nontemporal_load(base + (t + 8) * (NF/4) + tid + 256);
        #pragma unroll
        for (int t = 0; t < 8; ++t) a1 += x[t];
    }
    __syncthreads();   // covers cnt=0 and relbuf

    int nb = tid * 4;
    #pragma unroll
    for (int c = 0; c < 4; ++c)
        if (a0[c] != 0.f) {
            int p = atomicAdd(&cnt, 1);
            if (p < NZCAP) { nz_n[p] = nb + c; nz_v[p] = a0[c]; }
        }
    if (has1) {
        nb = (tid + 256) * 4;
        #pragma unroll
        for (int c = 0; c < 4; ++c)
            if (a1[c] != 0.f) {
                int p = atomicAdd(&cnt, 1);
                if (p < NZCAP) { nz_n[p] = nb + c; nz_v[p] = a1[c]; }
            }
    }
    __syncthreads();
    int c = min(cnt, NZCAP);
    if (tid == 0) cnt_g[bvm] = c;
    if (tid < NR) {                         // relation sums over t, from LDS
        float rs = 0.f;
        #pragma unroll
        for (int t = 0; t < MT; ++t) rs += relbuf[t * NR + tid];
        rsum_g[bvm * NR + tid] = rs;
    }
    for (int i = tid; i < c; i += 256) {
        nzn_g[bvm * NZCAP + i] = nz_n[i];
        nzv_g[bvm * NZCAP + i] = nz_v[i];
    }
}

// ---------- K2 (cooperative): reduce | gather | out, fused with grid syncs ----------
__global__ __launch_bounds__(256, 4) void k_tail(
        const float* __restrict__ emb, const float* __restrict__ W_edge,
        const float* __restrict__ WT_v, const float* __restrict__ WT_r,
        const float* __restrict__ b_v, const float* __restrict__ b_r,
        float* __restrict__ remb, float* __restrict__ redge,
        const int* __restrict__ cnt_g, const float* __restrict__ rsum_g,
        const int* __restrict__ nzn_g, const float* __restrict__ nzv_g,
        const float* __restrict__ attn_ws, const float* __restrict__ fsum_ws,
        const float* __restrict__ diag, const float* __restrict__ b_l,
        float* __restrict__ h_g, float* __restrict__ h_p,
        const float* __restrict__ fcWT, const float* __restrict__ fc_b,
        float* __restrict__ out) {
    __shared__ float smem[2 * NZCAP + 16];    // unioned across phases (8.3 KB)
    int blk = blockIdx.x;
    int tid = threadIdx.x;

    // ---- phase A: remb (8 rows/block) + redge ----
    if (blk < NODE_BLOCKS) {
        float* rows = smem;                   // [8][128]
        int n0 = blk * NPB;
        for (int i = tid; i < NPB * HID; i += 256)
            rows[i] = emb[(size_t)n0 * HID + i];
        __syncthreads();
        float bv0 = b_v[tid];
        float a0 = bv0, a1 = bv0, a2 = bv0, a3 = bv0;
        float a4 = bv0, a5 = bv0, a6 = bv0, a7 = bv0;
        #pragma unroll 4
        for (int k = 0; k < HID; ++k) {
            float w = WT_v[k * RED + tid];    // coalesced, L2-resident
            a0 += rows[0 * HID + k] * w;
            a1 += rows[1 * HID + k] * w;
            a2 += rows[2 * HID + k] * w;
            a3 += rows[3 * HID + k] * w;
            a4 += rows[4 * HID + k] * w;
            a5 += rows[5 * HID + k] * w;
            a6 += rows[6 * HID + k] * w;
            a7 += rows[7 * HID + k] * w;
        }
        float* dst = remb + (size_t)n0 * RED + tid;
        dst[0*RED] = a0; dst[1*RED] = a1; dst[2*RED] = a2; dst[3*RED] = a3;
        dst[4*RED] = a4; dst[5*RED] = a5; dst[6*RED] = a6; dst[7*RED] = a7;
        __syncthreads();
    } else if (blk < NODE_BLOCKS + NR) {
        int e = blk - NODE_BLOCKS;            // 0..10
        float* row = smem;
        if (tid < HID) row[tid] = W_edge[e * HID + tid];
        __syncthreads();
        float acc = b_r[tid];
        #pragma unroll 4
        for (int k = 0; k < HID; ++k)
            acc += row[k] * WT_r[k * RED + tid];
        redge[e * RED + tid] = acc;
        __syncthreads();
    }
    cg::this_grid().sync();

    // ---- phase B: sparse gather + diag/relu + atomic accumulate ----
    int*   nz_n = (int*)smem;
    float* nz_v = smem + NZCAP;
    float* rsum = smem + 2 * NZCAP;
    for (int bvm = blk; bvm < STREAM_BLOCKS; bvm += TAIL_GRID) {
        int b = bvm / (NV * MF);
        int c = cnt_g[bvm];
        if (tid < NR) rsum[tid] = rsum_g[bvm * NR + tid];
        for (int i = tid; i < c; i += 256) {
            nz_n[i] = nzn_g[bvm * NZCAP + i];
            nz_v[i] = nzv_g[bvm * NZCAP + i];
        }
        __syncthreads();
        int r = tid;
        float node = 0.f;
        for (int i = 0; i < c; ++i)
            node += nz_v[i] * remb[(size_t)nz_n[i] * RED + r];   // coalesced over r
        float edge = 0.f;
        #pragma unroll
        for (int j = 0; j < NR; ++j)
            edge += rsum[j] * redge[j * RED + r];
        float a  = attn_ws[bvm];
        float fs = fsum_ws[bvm];
        float agg = a * node + edge;
        float h = fmaxf(0.f, diag[r] * agg + b_l[r]);
        atomicAdd(&h_g[b * RED + r], h);
        atomicAdd(&h_p[b * RED + r], fs * h);
        __syncthreads();   // smem reused next iteration
    }
    cg::this_grid().sync();

    // ---- phase C: final FC + sigmoid ----
    if (blk < BS) {
        int b = blk;
        float* z     = smem;                  // 512
        float* part0 = smem + 2 * RED;        // 90
        float* part1 = part0 + OUTD;          // 90
        for (int j = tid; j < RED; j += 256) {
            z[j]       = h_g[b * RED + j];
            z[RED + j] = h_p[b * RED + j];
        }
        __syncthreads();
        int o = tid & 127, half = tid >> 7;
        if (o < OUTD) {
            float acc = 0.f;
            int j0 = half * RED;
            #pragma unroll 8
            for (int j = j0; j < j0 + RED; ++j)
                acc += z[j] * fcWT[j * OUTD + o];     // coalesced over o
            if (half) part1[o] = acc; else part0[o] = acc;
        }
        __syncthreads();
        if (tid < OUTD) {
            float acc = part0[tid] + part1[tid] + fc_b[tid];
            out[b * OUTD + tid] = 1.f / (1.f + expf(-acc));
        }
    }
}

extern "C" void kernel_launch(void* const* d_in, const int* in_sizes, int n_in,
                              void* d_out, int out_size, void* d_ws, size_t ws_size,
                              hipStream_t stream) {
    const float* feat    = (const float*)d_in[0];
    const float* nbr     = (const float*)d_in[1];
    const float* rel     = (const float*)d_in[2];
    const float* emb     = (const float*)d_in[3];
    const float* W_edge  = (const float*)d_in[4];
    const float* W_v     = (const float*)d_in[5];
    const float* W_r     = (const float*)d_in[6];
    const float* b_v     = (const float*)d_in[7];
    const float* b_r     = (const float*)d_in[8];
    const float* W_alpha = (const float*)d_in[9];
    const float* b_alpha = (const float*)d_in[10];
    const float* W_beta  = (const float*)d_in[11];
    const float* b_beta  = (const float*)d_in[12];
    const float* W_l     = (const float*)d_in[13];
    const float* b_l     = (const float*)d_in[14];
    const float* fc_W    = (const float*)d_in[15];
    const float* fc_b    = (const float*)d_in[16];

    float* ws    = (float*)d_ws;
    float* hg    = ws + WS_HG;
    float* hp    = ws + WS_HP;
    float* attn  = ws + WS_ATTN;
    float* fsum  = ws + WS_FSUM;
    float* remb  = ws + WS_REMB;
    float* redge = ws + WS_REDGE;
    float* WT_v  = ws + WS_WTV;
    float* WT_r  = ws + WS_WTR;
    float* fcWT  = ws + WS_FCWT;
    float* diag  = ws + WS_DIAG;
    int*   cnt_g = (int*)(ws + WS_CNT);
    float* rsum_g= ws + WS_RSUM;
    int*   nzn_g = (int*)(ws + WS_NZN);
    float* nzv_g = ws + WS_NZV;
    float* outp  = (float*)d_out;

    k_main<<<PREP_BLOCKS + ATTN_BLOCKS + STREAM_BLOCKS, 256, 0, stream>>>(
        nbr, rel, W_v, W_r, fc_W, W_l, feat, W_alpha, b_alpha, W_beta, b_beta,
        ws, WT_v, WT_r, fcWT, diag, cnt_g, rsum_g, nzn_g, nzv_g, attn, fsum);

    void* args[] = {
        (void*)&emb, (void*)&W_edge, (void*)&WT_v, (void*)&WT_r,
        (void*)&b_v, (void*)&b_r, (void*)&remb, (void*)&redge,
        (void*)&cnt_g, (void*)&rsum_g, (void*)&nzn_g, (void*)&nzv_g,
        (void*)&attn, (void*)&fsum, (void*)&diag, (void*)&b_l,
        (void*)&hg, (void*)&hp, (void*)&fcWT, (void*)&fc_b, (void*)&outp
    };
    hipLaunchCooperativeKernel((void*)k_tail, dim3(TAIL_GRID), dim3(256),
                               args, 0, stream);
}

// Round 7
// 473.665 us; speedup vs baseline: 1.4145x; 1.4145x over previous
//
#include <hip/hip_runtime.h>
#include <math.h>

#define BS   32
#define NV   6
#define MF   12
#define MT   16
#define NF   1992
#define NR   11
#define HID  128
#define RED  256
#define OUTD 90
#define GAMMA 0.1f
#define NZCAP 1024

typedef float f4_t __attribute__((ext_vector_type(4)));

// workspace layout (float offsets)
#define WS_HG    0                        // 32*256
#define WS_HP    (WS_HG + BS*RED)         // 32*256
#define WS_ATTN  (WS_HP + BS*RED)         // 2304
#define WS_FSUM  (WS_ATTN + BS*NV*MF)     // 2304
#define WS_REMB  (WS_FSUM + BS*NV*MF)     // 1992*256
#define WS_REDGE (WS_REMB + NF*RED)       // 11*256
#define WS_WTV   (WS_REDGE + NR*RED)      // 128*256  (W_v^T, k-major)
#define WS_WTR   (WS_WTV + HID*RED)       // 128*256  (W_r^T, k-major)
#define WS_FCWT  (WS_WTR + HID*RED)       // 512*90   (fc_W^T, j-major)
#define WS_DIAG  (WS_FCWT + 2*RED*OUTD)   // 256      (diag of W_l)
#define WS_CNT   (WS_DIAG + RED)          // 2304 ints
#define WS_RSUM  (WS_CNT + BS*NV*MF)      // 2304*11
#define WS_NZN   (WS_RSUM + BS*NV*MF*NR)  // 2304*1024 ints
#define WS_NZV   (WS_NZN + BS*NV*MF*NZCAP)// 2304*1024 floats

#define STREAM_BLOCKS (BS*NV*MF)          // 2304
#define N_ZERO (2*BS*RED)                 // 16384 (hg+hp contiguous)
#define N_WTV  (HID*RED)                  // 32768
#define N_WTR  (HID*RED)                  // 32768
#define N_FCWT (2*RED*OUTD)               // 46080
#define N_DIAG RED                        // 256
#define PREP_ELEMS (N_ZERO + N_WTV + N_WTR + N_FCWT + N_DIAG)   // 128256
#define PREP_BLOCKS (PREP_ELEMS / 256)                          // 501

// ---------- K1: nbr stream+compact  |  zero+transposes+diag  |  attention ----------
// NOTE: regular (cache-allocating) loads for the stream — NOT nontemporal.
__global__ __launch_bounds__(256) void k_stream_prep_attn(
        const float* __restrict__ nbr, const float* __restrict__ rel,
        const float* __restrict__ W_v, const float* __restrict__ W_r,
        const float* __restrict__ fc_W, const float* __restrict__ W_l,
        const float* __restrict__ feat, const float* __restrict__ W_alpha,
        const float* __restrict__ b_alpha, const float* __restrict__ W_beta,
        const float* __restrict__ b_beta,
        float* __restrict__ ws_base,
        float* __restrict__ WT_v, float* __restrict__ WT_r, float* __restrict__ fcWT,
        float* __restrict__ diag,
        int* __restrict__ cnt_g, float* __restrict__ rsum_g,
        int* __restrict__ nzn_g, float* __restrict__ nzv_g,
        float* __restrict__ attn_ws, float* __restrict__ fsum_ws) {
    int blk = blockIdx.x;
    int tid = threadIdx.x;

    if (blk < STREAM_BLOCKS) {
        // ---- the 294 MB long pole: stream nbr, sum over t, compact nonzeros ----
        int bvm = blk;
        __shared__ int   nz_n[NZCAP];
        __shared__ float nz_v[NZCAP];
        __shared__ float relbuf[MT * NR];       // 176 floats, contiguous in global
        __shared__ int   cnt;
        if (tid == 0) cnt = 0;
        if (tid < MT * NR / 4) {                // 44 float4 = whole rel slice
            ((f4_t*)relbuf)[tid] = ((const f4_t*)(rel + (size_t)bvm * MT * NR))[tid];
        }

        const f4_t* base = (const f4_t*)(nbr + (size_t)bvm * MT * NF);  // row = 498 f4
        f4_t x[8];
        f4_t a0 = (f4_t)(0.f);
        f4_t a1 = (f4_t)(0.f);
        // half 1: all threads, column tid (8-deep pipelined, twice)
        #pragma unroll
        for (int t = 0; t < 8; ++t) x[t] = base[t * (NF/4) + tid];
        #pragma unroll
        for (int t = 0; t < 8; ++t) a0 += x[t];
        #pragma unroll
        for (int t = 0; t < 8; ++t) x[t] = base[(t + 8) * (NF/4) + tid];
        #pragma unroll
        for (int t = 0; t < 8; ++t) a0 += x[t];
        // half 2: threads with tid+256 < 498
        const bool has1 = (tid + 256) < (NF / 4);
        if (has1) {
            #pragma unroll
            for (int t = 0; t < 8; ++t) x[t] = base[t * (NF/4) + tid + 256];
            #pragma unroll
            for (int t = 0; t < 8; ++t) a1 += x[t];
            #pragma unroll
            for (int t = 0; t < 8; ++t) x[t] = base[(t + 8) * (NF/4) + tid + 256];
            #pragma unroll
            for (int t = 0; t < 8; ++t) a1 += x[t];
        }
        __syncthreads();   // covers cnt=0 and relbuf

        int nb = tid * 4;
        #pragma unroll
        for (int c = 0; c < 4; ++c)
            if (a0[c] != 0.f) {
                int p = atomicAdd(&cnt, 1);
                if (p < NZCAP) { nz_n[p] = nb + c; nz_v[p] = a0[c]; }
            }
        if (has1) {
            nb = (tid + 256) * 4;
            #pragma unroll
            for (int c = 0; c < 4; ++c)
                if (a1[c] != 0.f) {
                    int p = atomicAdd(&cnt, 1);
                    if (p < NZCAP) { nz_n[p] = nb + c; nz_v[p] = a1[c]; }
                }
        }
        __syncthreads();
        int c = min(cnt, NZCAP);
        if (tid == 0) cnt_g[bvm] = c;
        if (tid < NR) {                         // relation sums over t, from LDS
            float rs = 0.f;
            #pragma unroll
            for (int t = 0; t < MT; ++t) rs += relbuf[t * NR + tid];
            rsum_g[bvm * NR + tid] = rs;
        }
        for (int i = tid; i < c; i += 256) {
            nzn_g[bvm * NZCAP + i] = nz_n[i];
            nzv_g[bvm * NZCAP + i] = nz_v[i];
        }
        return;
    }
    blk -= STREAM_BLOCKS;

    if (blk < PREP_BLOCKS) {
        int i = blk * 256 + tid;
        if (i < N_ZERO) {                          // zero hg+hp
            ws_base[i] = 0.f;
        } else if (i < N_ZERO + N_WTV) {           // WT_v[k*256+r] = W_v[r*128+k]
            int j = i - N_ZERO;
            int k = j >> 8, r = j & 255;
            WT_v[j] = W_v[r * HID + k];
        } else if (i < N_ZERO + N_WTV + N_WTR) {
            int j = i - (N_ZERO + N_WTV);
            int k = j >> 8, r = j & 255;
            WT_r[j] = W_r[r * HID + k];
        } else if (i < N_ZERO + N_WTV + N_WTR + N_FCWT) {
            int j = i - (N_ZERO + N_WTV + N_WTR);  // j = jj*90 + o
            int jj = j / OUTD, o = j - jj * OUTD;
            fcWT[j] = fc_W[o * (2 * RED) + jj];
        } else {
            int j = i - (N_ZERO + N_WTV + N_WTR + N_FCWT);
            diag[j] = W_l[(size_t)j * RED + j];
        }
        return;
    }

    // ---- attention: one block per (b,v), one wave per m ----
    int bv   = blk - PREP_BLOCKS;                  // 0..191
    int v    = bv % NV;
    int wave = tid >> 6;
    int lane = tid & 63;
    __shared__ float dot12[MF], fs12[MF];
    const float* base = feat + (size_t)bv * MF * NF;
    for (int m = wave; m < MF; m += 4) {
        const float4* rw = (const float4*)(base + (size_t)m * NF);   // 498 float4
        const float4* wa = (const float4*)W_alpha;
        float da = 0.f, fs = 0.f;
        for (int i = lane; i < NF / 4; i += 64) {
            float4 x = rw[i];
            float4 w = wa[i];
            da += w.x * x.x + w.y * x.y + w.z * x.z + w.w * x.w;
            fs += x.x + x.y + x.z + x.w;
        }
        #pragma unroll
        for (int off = 32; off > 0; off >>= 1) {
            da += __shfl_xor(da, off);
            fs += __shfl_xor(fs, off);
        }
        if (lane == 0) { dot12[m] = da; fs12[m] = fs; }
    }
    __syncthreads();
    if (tid == 0) {
        float logits[MF];
        float mx = -1e30f;
        for (int m = 0; m < MF; ++m) { logits[m] = dot12[m] + b_alpha[m]; mx = fmaxf(mx, logits[m]); }
        float s = 0.f;
        for (int m = 0; m < MF; ++m) { logits[m] = expf(logits[m] - mx); s += logits[m]; }
        float inv = 1.f / s;
        float bdot = 0.f;
        for (int m = 0; m < MF; ++m) { logits[m] *= inv; bdot += W_beta[m] * logits[m]; }
        float lamb = expf(-GAMMA * (float)(NV - v));
        float beta = tanhf(bdot + b_beta[v]) * lamb;
        for (int m = 0; m < MF; ++m) {
            attn_ws[bv * MF + m] = logits[m] * beta;
            fsum_ws[bv * MF + m] = fs12[m];
        }
    }
}

// ---------- K2: reduced_emb (8 rows/block) + reduced_edge ----------
#define NPB 8
#define NODE_BLOCKS (NF / NPB)   // 249
__global__ __launch_bounds__(256) void k_reduce(
        const float* __restrict__ emb, const float* __restrict__ W_edge,
        const float* __restrict__ WT_v, const float* __restrict__ WT_r,
        const float* __restrict__ b_v, const float* __restrict__ b_r,
        float* __restrict__ remb, float* __restrict__ redge) {
    int blk = blockIdx.x;
    int tid = threadIdx.x;                    // r = tid
    if (blk < NODE_BLOCKS) {
        __shared__ float rows[NPB][HID];
        int n0 = blk * NPB;
        for (int i = tid; i < NPB * HID; i += 256)
            rows[i >> 7][i & 127] = emb[(size_t)n0 * HID + i];
        __syncthreads();
        float bv0 = b_v[tid];
        float a0 = bv0, a1 = bv0, a2 = bv0, a3 = bv0;
        float a4 = bv0, a5 = bv0, a6 = bv0, a7 = bv0;
        #pragma unroll 4
        for (int k = 0; k < HID; ++k) {
            float w = WT_v[k * RED + tid];    // coalesced, L2-resident
            a0 += rows[0][k] * w;
            a1 += rows[1][k] * w;
            a2 += rows[2][k] * w;
            a3 += rows[3][k] * w;
            a4 += rows[4][k] * w;
            a5 += rows[5][k] * w;
            a6 += rows[6][k] * w;
            a7 += rows[7][k] * w;
        }
        float* dst = remb + (size_t)n0 * RED + tid;
        dst[0*RED] = a0; dst[1*RED] = a1; dst[2*RED] = a2; dst[3*RED] = a3;
        dst[4*RED] = a4; dst[5*RED] = a5; dst[6*RED] = a6; dst[7*RED] = a7;
    } else {
        int e = blk - NODE_BLOCKS;            // 0..10
        __shared__ float row[HID];
        if (tid < HID) row[tid] = W_edge[e * HID + tid];
        __syncthreads();
        float acc = b_r[tid];
        #pragma unroll 4
        for (int k = 0; k < HID; ++k)
            acc += row[k] * WT_r[k * RED + tid];
        redge[e * RED + tid] = acc;
    }
}

// ---------- K3: sparse gather + diag/relu + atomic accumulate ----------
__global__ __launch_bounds__(256) void k_gather(
        const float* __restrict__ remb, const float* __restrict__ redge,
        const int* __restrict__ cnt_g, const float* __restrict__ rsum_g,
        const int* __restrict__ nzn_g, const float* __restrict__ nzv_g,
        const float* __restrict__ attn_ws, const float* __restrict__ fsum_ws,
        const float* __restrict__ diag, const float* __restrict__ b_l,
        float* __restrict__ h_g, float* __restrict__ h_p) {
    int bvm = blockIdx.x;                     // 0..2303
    int b   = bvm / (NV * MF);
    int tid = threadIdx.x;                    // r = tid
    __shared__ int   nz_n[NZCAP];
    __shared__ float nz_v[NZCAP];
    __shared__ float rsum[NR];
    int c = cnt_g[bvm];
    if (tid < NR) rsum[tid] = rsum_g[bvm * NR + tid];
    for (int i = tid; i < c; i += 256) {
        nz_n[i] = nzn_g[bvm * NZCAP + i];
        nz_v[i] = nzv_g[bvm * NZCAP + i];
    }
    __syncthreads();
    int r = tid;
    float node = 0.f;
    for (int i = 0; i < c; ++i)
        node += nz_v[i] * remb[(size_t)nz_n[i] * RED + r];   // coalesced over r
    float edge = 0.f;
    #pragma unroll
    for (int j = 0; j < NR; ++j)
        edge += rsum[j] * redge[j * RED + r];
    float a  = attn_ws[bvm];
    float fs = fsum_ws[bvm];
    float agg = a * node + edge;
    float h = fmaxf(0.f, diag[r] * agg + b_l[r]);
    atomicAdd(&h_g[b * RED + r], h);
    atomicAdd(&h_p[b * RED + r], fs * h);
}

// ---------- K4: final FC + sigmoid ----------
__global__ __launch_bounds__(256) void k_out(
        const float* __restrict__ h_g, const float* __restrict__ h_p,
        const float* __restrict__ fcWT, const float* __restrict__ fc_b,
        float* __restrict__ out) {
    int b   = blockIdx.x;
    int tid = threadIdx.x;                    // 256
    __shared__ float z[2 * RED];
    __shared__ float part[2][OUTD];
    for (int j = tid; j < RED; j += 256) {
        z[j]       = h_g[b * RED + j];
        z[RED + j] = h_p[b * RED + j];
    }
    __syncthreads();
    int o = tid & 127, half = tid >> 7;
    if (o < OUTD) {
        float acc = 0.f;
        int j0 = half * RED;
        #pragma unroll 8
        for (int j = j0; j < j0 + RED; ++j)
            acc += z[j] * fcWT[j * OUTD + o];     // coalesced over o
        part[half][o] = acc;
    }
    __syncthreads();
    if (tid < OUTD) {
        float acc = part[0][tid] + part[1][tid] + fc_b[tid];
        out[b * OUTD + tid] = 1.f / (1.f + expf(-acc));
    }
}

extern "C" void kernel_launch(void* const* d_in, const int* in_sizes, int n_in,
                              void* d_out, int out_size, void* d_ws, size_t ws_size,
                              hipStream_t stream) {
    const float* feat    = (const float*)d_in[0];
    const float* nbr     = (const float*)d_in[1];
    const float* rel     = (const float*)d_in[2];
    const float* emb     = (const float*)d_in[3];
    const float* W_edge  = (const float*)d_in[4];
    const float* W_v     = (const float*)d_in[5];
    const float* W_r     = (const float*)d_in[6];
    const float* b_v     = (const float*)d_in[7];
    const float* b_r     = (const float*)d_in[8];
    const float* W_alpha = (const float*)d_in[9];
    const float* b_alpha = (const float*)d_in[10];
    const float* W_beta  = (const float*)d_in[11];
    const float* b_beta  = (const float*)d_in[12];
    const float* W_l     = (const float*)d_in[13];
    const float* b_l     = (const float*)d_in[14];
    const float* fc_W    = (const float*)d_in[15];
    const float* fc_b    = (const float*)d_in[16];

    float* ws    = (float*)d_ws;
    float* hg    = ws + WS_HG;
    float* hp    = ws + WS_HP;
    float* attn  = ws + WS_ATTN;
    float* fsum  = ws + WS_FSUM;
    float* remb  = ws + WS_REMB;
    float* redge = ws + WS_REDGE;
    float* WT_v  = ws + WS_WTV;
    float* WT_r  = ws + WS_WTR;
    float* fcWT  = ws + WS_FCWT;
    float* diag  = ws + WS_DIAG;
    int*   cnt_g = (int*)(ws + WS_CNT);
    float* rsum_g= ws + WS_RSUM;
    int*   nzn_g = (int*)(ws + WS_NZN);
    float* nzv_g = ws + WS_NZV;

    k_stream_prep_attn<<<STREAM_BLOCKS + PREP_BLOCKS + BS * NV, 256, 0, stream>>>(
        nbr, rel, W_v, W_r, fc_W, W_l, feat, W_alpha, b_alpha, W_beta, b_beta,
        ws, WT_v, WT_r, fcWT, diag, cnt_g, rsum_g, nzn_g, nzv_g, attn, fsum);
    k_reduce<<<NODE_BLOCKS + NR, 256, 0, stream>>>(
        emb, W_edge, WT_v, WT_r, b_v, b_r, remb, redge);
    k_gather<<<BS * NV * MF, 256, 0, stream>>>(
        remb, redge, cnt_g, rsum_g, nzn_g, nzv_g, attn, fsum, diag, b_l, hg, hp);
    k_out<<<BS, 256, 0, stream>>>(hg, hp, fcWT, fc_b, (float*)d_out);
}

// Round 8
// 450.428 us; speedup vs baseline: 1.4875x; 1.0516x over previous
//
#include <hip/hip_runtime.h>
#include <math.h>

#define BS   32
#define NV   6
#define MF   12
#define MT   16
#define NF   1992
#define NR   11
#define HID  128
#define RED  256
#define OUTD 90
#define GAMMA 0.1f
#define NZCAP 1024

typedef float f4_t __attribute__((ext_vector_type(4)));

// workspace layout (float offsets)
#define WS_HG    0                        // 32*256
#define WS_HP    (WS_HG + BS*RED)         // 32*256
#define WS_ATTN  (WS_HP + BS*RED)         // 2304
#define WS_FSUM  (WS_ATTN + BS*NV*MF)     // 2304
#define WS_REMB  (WS_FSUM + BS*NV*MF)     // 1992*256
#define WS_REDGE (WS_REMB + NF*RED)       // 11*256
#define WS_WTV   (WS_REDGE + NR*RED)      // 128*256  (W_v^T, k-major)
#define WS_WTR   (WS_WTV + HID*RED)       // 128*256  (W_r^T, k-major)
#define WS_FCWT  (WS_WTR + HID*RED)       // 512*90   (fc_W^T, j-major)
#define WS_DIAG  (WS_FCWT + 2*RED*OUTD)   // 256      (diag of W_l)
#define WS_CNT   (WS_DIAG + RED)          // 2304 ints
#define WS_RSUM  (WS_CNT + BS*NV*MF)      // 2304*11
#define WS_NZN   (WS_RSUM + BS*NV*MF*NR)  // 2304*1024 ints
#define WS_NZV   (WS_NZN + BS*NV*MF*NZCAP)// 2304*1024 floats

#define STREAM_BLOCKS (BS*NV*MF)          // 2304
#define N_ZERO (2*BS*RED)                 // 16384 (hg+hp contiguous)
#define N_WTV  (HID*RED)                  // 32768
#define N_WTR  (HID*RED)                  // 32768
#define N_FCWT (2*RED*OUTD)               // 46080
#define N_DIAG RED                        // 256
#define PREP_ELEMS (N_ZERO + N_WTV + N_WTR + N_FCWT + N_DIAG)   // 128256
#define PREP_BLOCKS (PREP_ELEMS / 256)                          // 501

// ---------- K1: nbr stream+compact  |  zero+transposes+diag  |  attention ----------
// nontemporal loads for the 294 MB stream: measured +26us when removed (R7).
__global__ __launch_bounds__(256) void k_stream_prep_attn(
        const float* __restrict__ nbr, const float* __restrict__ rel,
        const float* __restrict__ W_v, const float* __restrict__ W_r,
        const float* __restrict__ fc_W, const float* __restrict__ W_l,
        const float* __restrict__ feat, const float* __restrict__ W_alpha,
        const float* __restrict__ b_alpha, const float* __restrict__ W_beta,
        const float* __restrict__ b_beta,
        float* __restrict__ ws_base,
        float* __restrict__ WT_v, float* __restrict__ WT_r, float* __restrict__ fcWT,
        float* __restrict__ diag,
        int* __restrict__ cnt_g, float* __restrict__ rsum_g,
        int* __restrict__ nzn_g, float* __restrict__ nzv_g,
        float* __restrict__ attn_ws, float* __restrict__ fsum_ws) {
    int blk = blockIdx.x;
    int tid = threadIdx.x;

    if (blk < STREAM_BLOCKS) {
        // ---- the 294 MB long pole: stream nbr, sum over t, compact nonzeros ----
        int bvm = blk;
        __shared__ int   nz_n[NZCAP];
        __shared__ float nz_v[NZCAP];
        __shared__ int   cnt;
        if (tid == 0) cnt = 0;
        const f4_t* base = (const f4_t*)(nbr + (size_t)bvm * MT * NF);  // row = 498 f4
        f4_t a0 = (f4_t)(0.f);
        f4_t a1 = (f4_t)(0.f);
        const bool has1 = (tid + 256) < (NF / 4);
        #pragma unroll 4
        for (int t = 0; t < MT; ++t) {
            const f4_t* r4 = base + t * (NF / 4);
            a0 += __builtin_nontemporal_load(r4 + tid);
            if (has1) a1 += __builtin_nontemporal_load(r4 + tid + 256);
        }
        float rs = 0.f;
        if (tid < NR) {
            const float* rb = rel + (size_t)bvm * MT * NR;
            #pragma unroll
            for (int t = 0; t < MT; ++t) rs += rb[t * NR + tid];
        }
        __syncthreads();   // covers cnt=0
        int nb = tid * 4;
        #pragma unroll
        for (int c = 0; c < 4; ++c)
            if (a0[c] != 0.f) {
                int p = atomicAdd(&cnt, 1);
                if (p < NZCAP) { nz_n[p] = nb + c; nz_v[p] = a0[c]; }
            }
        if (has1) {
            nb = (tid + 256) * 4;
            #pragma unroll
            for (int c = 0; c < 4; ++c)
                if (a1[c] != 0.f) {
                    int p = atomicAdd(&cnt, 1);
                    if (p < NZCAP) { nz_n[p] = nb + c; nz_v[p] = a1[c]; }
                }
        }
        __syncthreads();
        int c = min(cnt, NZCAP);
        if (tid == 0) cnt_g[bvm] = c;
        if (tid < NR) rsum_g[bvm * NR + tid] = rs;
        for (int i = tid; i < c; i += 256) {
            nzn_g[bvm * NZCAP + i] = nz_n[i];
            nzv_g[bvm * NZCAP + i] = nz_v[i];
        }
        return;
    }
    blk -= STREAM_BLOCKS;

    if (blk < PREP_BLOCKS) {
        int i = blk * 256 + tid;
        if (i < N_ZERO) {                          // zero hg+hp
            ws_base[i] = 0.f;
        } else if (i < N_ZERO + N_WTV) {           // WT_v[k*256+r] = W_v[r*128+k]
            int j = i - N_ZERO;
            int k = j >> 8, r = j & 255;
            WT_v[j] = W_v[r * HID + k];
        } else if (i < N_ZERO + N_WTV + N_WTR) {
            int j = i - (N_ZERO + N_WTV);
            int k = j >> 8, r = j & 255;
            WT_r[j] = W_r[r * HID + k];
        } else if (i < N_ZERO + N_WTV + N_WTR + N_FCWT) {
            int j = i - (N_ZERO + N_WTV + N_WTR);  // j = jj*90 + o
            int jj = j / OUTD, o = j - jj * OUTD;
            fcWT[j] = fc_W[o * (2 * RED) + jj];
        } else {
            int j = i - (N_ZERO + N_WTV + N_WTR + N_FCWT);
            diag[j] = W_l[(size_t)j * RED + j];
        }
        return;
    }

    // ---- attention: one block per (b,v), one wave per m ----
    int bv   = blk - PREP_BLOCKS;                  // 0..191
    int v    = bv % NV;
    int wave = tid >> 6;
    int lane = tid & 63;
    __shared__ float dot12[MF], fs12[MF];
    const float* base = feat + (size_t)bv * MF * NF;
    for (int m = wave; m < MF; m += 4) {
        const float4* rw = (const float4*)(base + (size_t)m * NF);   // 498 float4
        const float4* wa = (const float4*)W_alpha;
        float da = 0.f, fs = 0.f;
        for (int i = lane; i < NF / 4; i += 64) {
            float4 x = rw[i];
            float4 w = wa[i];
            da += w.x * x.x + w.y * x.y + w.z * x.z + w.w * x.w;
            fs += x.x + x.y + x.z + x.w;
        }
        #pragma unroll
        for (int off = 32; off > 0; off >>= 1) {
            da += __shfl_xor(da, off);
            fs += __shfl_xor(fs, off);
        }
        if (lane == 0) { dot12[m] = da; fs12[m] = fs; }
    }
    __syncthreads();
    if (tid == 0) {
        float logits[MF];
        float mx = -1e30f;
        for (int m = 0; m < MF; ++m) { logits[m] = dot12[m] + b_alpha[m]; mx = fmaxf(mx, logits[m]); }
        float s = 0.f;
        for (int m = 0; m < MF; ++m) { logits[m] = expf(logits[m] - mx); s += logits[m]; }
        float inv = 1.f / s;
        float bdot = 0.f;
        for (int m = 0; m < MF; ++m) { logits[m] *= inv; bdot += W_beta[m] * logits[m]; }
        float lamb = expf(-GAMMA * (float)(NV - v));
        float beta = tanhf(bdot + b_beta[v]) * lamb;
        for (int m = 0; m < MF; ++m) {
            attn_ws[bv * MF + m] = logits[m] * beta;
            fsum_ws[bv * MF + m] = fs12[m];
        }
    }
}

// ---------- K2: reduced_emb (8 rows/block) + reduced_edge ----------
#define NPB 8
#define NODE_BLOCKS (NF / NPB)   // 249
__global__ __launch_bounds__(256) void k_reduce(
        const float* __restrict__ emb, const float* __restrict__ W_edge,
        const float* __restrict__ WT_v, const float* __restrict__ WT_r,
        const float* __restrict__ b_v, const float* __restrict__ b_r,
        float* __restrict__ remb, float* __restrict__ redge) {
    int blk = blockIdx.x;
    int tid = threadIdx.x;                    // r = tid
    if (blk < NODE_BLOCKS) {
        __shared__ float rows[NPB][HID];
        int n0 = blk * NPB;
        for (int i = tid; i < NPB * HID; i += 256)
            rows[i >> 7][i & 127] = emb[(size_t)n0 * HID + i];
        __syncthreads();
        float bv0 = b_v[tid];
        float a0 = bv0, a1 = bv0, a2 = bv0, a3 = bv0;
        float a4 = bv0, a5 = bv0, a6 = bv0, a7 = bv0;
        #pragma unroll 4
        for (int k = 0; k < HID; ++k) {
            float w = WT_v[k * RED + tid];    // coalesced, L2-resident
            a0 += rows[0][k] * w;
            a1 += rows[1][k] * w;
            a2 += rows[2][k] * w;
            a3 += rows[3][k] * w;
            a4 += rows[4][k] * w;
            a5 += rows[5][k] * w;
            a6 += rows[6][k] * w;
            a7 += rows[7][k] * w;
        }
        float* dst = remb + (size_t)n0 * RED + tid;
        dst[0*RED] = a0; dst[1*RED] = a1; dst[2*RED] = a2; dst[3*RED] = a3;
        dst[4*RED] = a4; dst[5*RED] = a5; dst[6*RED] = a6; dst[7*RED] = a7;
    } else {
        int e = blk - NODE_BLOCKS;            // 0..10
        __shared__ float row[HID];
        if (tid < HID) row[tid] = W_edge[e * HID + tid];
        __syncthreads();
        float acc = b_r[tid];
        #pragma unroll 4
        for (int k = 0; k < HID; ++k)
            acc += row[k] * WT_r[k * RED + tid];
        redge[e * RED + tid] = acc;
    }
}

// ---------- K3: sparse gather + diag/relu + atomic accumulate ----------
__global__ __launch_bounds__(256) void k_gather(
        const float* __restrict__ remb, const float* __restrict__ redge,
        const int* __restrict__ cnt_g, const float* __restrict__ rsum_g,
        const int* __restrict__ nzn_g, const float* __restrict__ nzv_g,
        const float* __restrict__ attn_ws, const float* __restrict__ fsum_ws,
        const float* __restrict__ diag, const float* __restrict__ b_l,
        float* __restrict__ h_g, float* __restrict__ h_p) {
    int bvm = blockIdx.x;                     // 0..2303
    int b   = bvm / (NV * MF);
    int tid = threadIdx.x;                    // r = tid
    __shared__ int   nz_n[NZCAP];
    __shared__ float nz_v[NZCAP];
    __shared__ float rsum[NR];
    int c = cnt_g[bvm];
    if (tid < NR) rsum[tid] = rsum_g[bvm * NR + tid];
    for (int i = tid; i < c; i += 256) {
        nz_n[i] = nzn_g[bvm * NZCAP + i];
        nz_v[i] = nzv_g[bvm * NZCAP + i];
    }
    __syncthreads();
    int r = tid;
    float node = 0.f;
    for (int i = 0; i < c; ++i)
        node += nz_v[i] * remb[(size_t)nz_n[i] * RED + r];   // coalesced over r
    float edge = 0.f;
    #pragma unroll
    for (int j = 0; j < NR; ++j)
        edge += rsum[j] * redge[j * RED + r];
    float a  = attn_ws[bvm];
    float fs = fsum_ws[bvm];
    float agg = a * node + edge;
    float h = fmaxf(0.f, diag[r] * agg + b_l[r]);
    atomicAdd(&h_g[b * RED + r], h);
    atomicAdd(&h_p[b * RED + r], fs * h);
}

// ---------- K4: final FC + sigmoid ----------
__global__ __launch_bounds__(256) void k_out(
        const float* __restrict__ h_g, const float* __restrict__ h_p,
        const float* __restrict__ fcWT, const float* __restrict__ fc_b,
        float* __restrict__ out) {
    int b   = blockIdx.x;
    int tid = threadIdx.x;                    // 256
    __shared__ float z[2 * RED];
    __shared__ float part[2][OUTD];
    for (int j = tid; j < RED; j += 256) {
        z[j]       = h_g[b * RED + j];
        z[RED + j] = h_p[b * RED + j];
    }
    __syncthreads();
    int o = tid & 127, half = tid >> 7;
    if (o < OUTD) {
        float acc = 0.f;
        int j0 = half * RED;
        #pragma unroll 8
        for (int j = j0; j < j0 + RED; ++j)
            acc += z[j] * fcWT[j * OUTD + o];     // coalesced over o
        part[half][o] = acc;
    }
    __syncthreads();
    if (tid < OUTD) {
        float acc = part[0][tid] + part[1][tid] + fc_b[tid];
        out[b * OUTD + tid] = 1.f / (1.f + expf(-acc));
    }
}

extern "C" void kernel_launch(void* const* d_in, const int* in_sizes, int n_in,
                              void* d_out, int out_size, void* d_ws, size_t ws_size,
                              hipStream_t stream) {
    const float* feat    = (const float*)d_in[0];
    const float* nbr     = (const float*)d_in[1];
    const float* rel     = (const float*)d_in[2];
    const float* emb     = (const float*)d_in[3];
    const float* W_edge  = (const float*)d_in[4];
    const float* W_v     = (const float*)d_in[5];
    const float* W_r     = (const float*)d_in[6];
    const float* b_v     = (const float*)d_in[7];
    const float* b_r     = (const float*)d_in[8];
    const float* W_alpha = (const float*)d_in[9];
    const float* b_alpha = (const float*)d_in[10];
    const float* W_beta  = (const float*)d_in[11];
    const float* b_beta  = (const float*)d_in[12];
    const float* W_l     = (const float*)d_in[13];
    const float* b_l     = (const float*)d_in[14];
    const float* fc_W    = (const float*)d_in[15];
    const float* fc_b    = (const float*)d_in[16];

    float* ws    = (float*)d_ws;
    float* hg    = ws + WS_HG;
    float* hp    = ws + WS_HP;
    float* attn  = ws + WS_ATTN;
    float* fsum  = ws + WS_FSUM;
    float* remb  = ws + WS_REMB;
    float* redge = ws + WS_REDGE;
    float* WT_v  = ws + WS_WTV;
    float* WT_r  = ws + WS_WTR;
    float* fcWT  = ws + WS_FCWT;
    float* diag  = ws + WS_DIAG;
    int*   cnt_g = (int*)(ws + WS_CNT);
    float* rsum_g= ws + WS_RSUM;
    int*   nzn_g = (int*)(ws + WS_NZN);
    float* nzv_g = ws + WS_NZV;

    k_stream_prep_attn<<<STREAM_BLOCKS + PREP_BLOCKS + BS * NV, 256, 0, stream>>>(
        nbr, rel, W_v, W_r, fc_W, W_l, feat, W_alpha, b_alpha, W_beta, b_beta,
        ws, WT_v, WT_r, fcWT, diag, cnt_g, rsum_g, nzn_g, nzv_g, attn, fsum);
    k_reduce<<<NODE_BLOCKS + NR, 256, 0, stream>>>(
        emb, W_edge, WT_v, WT_r, b_v, b_r, remb, redge);
    k_gather<<<BS * NV * MF, 256, 0, stream>>>(
        remb, redge, cnt_g, rsum_g, nzn_g, nzv_g, attn, fsum, diag, b_l, hg, hp);
    k_out<<<BS, 256, 0, stream>>>(hg, hp, fcWT, fc_b, (float*)d_out);
}